// Round 2
// baseline (1043.012 us; speedup 1.0000x reference)
//
#include <hip/hip_runtime.h>

#define F 128
#define MTOT 16
#define WDIM 132   // F + NL

typedef __bf16 bf16x8 __attribute__((ext_vector_type(8)));
typedef float f32x4 __attribute__((ext_vector_type(4)));

union U16x8 { uint4 u; bf16x8 b; unsigned short s[8]; };

__device__ __forceinline__ unsigned short f2bf(float f) {
    unsigned int u = __float_as_uint(f);
    u += 0x7FFFu + ((u >> 16) & 1u);
    return (unsigned short)(u >> 16);
}

// Transpose + bf16-convert the 128x128 top-left block of W into d_ws:
// Wt[n][k] = bf16(W[k][n]), dense stride 128.
__global__ void prep_wt(const float* __restrict__ W, unsigned short* __restrict__ Wt) {
    int tid = blockIdx.x * blockDim.x + threadIdx.x;
    if (tid < F * F) {
        int nn = tid >> 7, kk = tid & 127;
        Wt[nn * F + kk] = f2bf(W[kk * WDIM + nn]);
    }
}

__global__ __launch_bounds__(256, 2)
void interaction_kernel(const float* __restrict__ x, const float* __restrict__ chi,
                        const float* __restrict__ W, const float* __restrict__ b,
                        const unsigned short* __restrict__ Wt,
                        float* __restrict__ a1_out, float* __restrict__ chi_out,
                        int n) {
    __shared__ __align__(16) unsigned short A_s[128 * 136];  // x tile bf16, pad 8
    __shared__ __align__(16) float chi_s[128 * 16];
    __shared__ __align__(16) float dchi_s[128 * 4];
    __shared__ __align__(16) float Wda_s[4 * 128];   // W[128+l][0:128]
    __shared__ __align__(16) float Wb1t_s[4 * 128];  // W[k][128+j] laid out [j][k]
    __shared__ __align__(16) float Wdd_s[16];        // W[128+l][128+j] = [l*4+j]
    __shared__ __align__(16) float b_s[WDIM];
    __shared__ __align__(16) float b1_s[128 * 4];

    const int t = threadIdx.x;
    const long long row0 = (long long)blockIdx.x * 128;

    // ---- stage x tile -> A_s (fp32 -> bf16) ----
#pragma unroll
    for (int i = 0; i < 16; ++i) {
        int e4 = i * 256 + t;          // float4 index in tile (0..4095)
        int row = e4 >> 5;             // 32 float4 per 128-float row
        int c4  = e4 & 31;
        long long rg = row0 + row;
        float4 v = make_float4(0.f, 0.f, 0.f, 0.f);
        if (rg < n) v = *reinterpret_cast<const float4*>(x + rg * F + c4 * 4);
        ushort4 o;
        o.x = f2bf(v.x); o.y = f2bf(v.y); o.z = f2bf(v.z); o.w = f2bf(v.w);
        *reinterpret_cast<ushort4*>(&A_s[row * 136 + c4 * 4]) = o;
    }
    // ---- stage chi tile ----
#pragma unroll
    for (int i = 0; i < 2; ++i) {
        int e4 = i * 256 + t;          // 0..511 float4s (128 rows x 16)
        int row = e4 >> 2;
        long long rg = row0 + row;
        float4 v = make_float4(0.f, 0.f, 0.f, 0.f);
        if (rg < n) v = *reinterpret_cast<const float4*>(chi + rg * MTOT + (e4 & 3) * 4);
        *reinterpret_cast<float4*>(&chi_s[e4 * 4]) = v;
    }
    // ---- stage small W pieces + b ----
    if (t < WDIM) b_s[t] = b[t];
    if (t < 16) Wdd_s[t] = W[(F + (t >> 2)) * WDIM + F + (t & 3)];
    if (t < 128) {
#pragma unroll
        for (int l = 0; l < 4; ++l) Wda_s[l * 128 + t] = W[(F + l) * WDIM + t];
#pragma unroll
        for (int j = 0; j < 4; ++j) Wb1t_s[j * 128 + t] = W[t * WDIM + F + j];
    }
    __syncthreads();

    // ---- d_chi (fp32): segment sums of chi^2, degrees (1,3,5,7) ----
    if (t < 128) {
        const float* c = &chi_s[t * 16];
        float s0 = c[0] * c[0];
        float s1 = c[1] * c[1] + c[2] * c[2] + c[3] * c[3];
        float s2 = 0.f;
#pragma unroll
        for (int m = 4; m < 9; ++m) s2 += c[m] * c[m];
        float s3 = 0.f;
#pragma unroll
        for (int m = 9; m < 16; ++m) s3 += c[m] * c[m];
        *reinterpret_cast<float4*>(&dchi_s[t * 4]) = make_float4(s0, s1, s2, s3);
    }
    __syncthreads();   // dchi_s visible to all threads (b1 pass needs it)

    // ---- b1 (fp32, from ORIGINAL fp32 x in global — L2-resident re-read).
    // bf16 x would give b1 error ~0.1-0.2 which chi (|chi|~5) amplifies past
    // the chi_out threshold; fp32 keeps chi_out at fp32 rounding (~1e-4).
    // Each thread: one row (t>>1), two of the 4 b1 columns ((t&1)*2 .. +1).
    {
        const int row = t >> 1;
        const int jp = (t & 1) * 2;
        const long long rg = row0 + row;
        float acc0 = 0.f, acc1 = 0.f;
        if (rg < n) {
            const float4* xr = reinterpret_cast<const float4*>(x + rg * F);
#pragma unroll
            for (int k4 = 0; k4 < 32; ++k4) {
                float4 xv = xr[k4];
                float4 w0 = *reinterpret_cast<const float4*>(&Wb1t_s[jp * 128 + k4 * 4]);
                float4 w1 = *reinterpret_cast<const float4*>(&Wb1t_s[(jp + 1) * 128 + k4 * 4]);
                acc0 += xv.x * w0.x + xv.y * w0.y + xv.z * w0.z + xv.w * w0.w;
                acc1 += xv.x * w1.x + xv.y * w1.y + xv.z * w1.z + xv.w * w1.w;
            }
        }
        const float* dr = &dchi_s[row * 4];
        const float d0 = dr[0], d1 = dr[1], d2 = dr[2], d3 = dr[3];
        acc0 += d0 * Wdd_s[0 * 4 + jp] + d1 * Wdd_s[1 * 4 + jp]
              + d2 * Wdd_s[2 * 4 + jp] + d3 * Wdd_s[3 * 4 + jp] + b_s[F + jp];
        acc1 += d0 * Wdd_s[0 * 4 + jp + 1] + d1 * Wdd_s[1 * 4 + jp + 1]
              + d2 * Wdd_s[2 * 4 + jp + 1] + d3 * Wdd_s[3 * 4 + jp + 1] + b_s[F + jp + 1];
        b1_s[row * 4 + jp] = acc0;
        b1_s[row * 4 + jp + 1] = acc1;
    }

    // ---- MFMA main GEMM: (128 rows x 128k) x (128k x 128n) ----
    const int lane = t & 63;
    const int w = t >> 6;
    const int wm = (w & 1) * 64;
    const int wn = (w >> 1) * 64;
    const int q = lane >> 4;
    const int l16 = lane & 15;

    f32x4 acc[4][4];
#pragma unroll
    for (int mi = 0; mi < 4; ++mi)
#pragma unroll
        for (int ni = 0; ni < 4; ++ni)
            acc[mi][ni] = (f32x4){0.f, 0.f, 0.f, 0.f};

#pragma unroll
    for (int ks = 0; ks < 4; ++ks) {
        const int kof = ks * 32 + q * 8;
        bf16x8 a[4], bb[4];
#pragma unroll
        for (int mi = 0; mi < 4; ++mi) {
            U16x8 u;
            u.u = *reinterpret_cast<const uint4*>(&A_s[(wm + mi * 16 + l16) * 136 + kof]);
            a[mi] = u.b;
        }
#pragma unroll
        for (int ni = 0; ni < 4; ++ni) {
            U16x8 u;
            u.u = *reinterpret_cast<const uint4*>(&Wt[(wn + ni * 16 + l16) * F + kof]);
            bb[ni] = u.b;
        }
#pragma unroll
        for (int mi = 0; mi < 4; ++mi)
#pragma unroll
            for (int ni = 0; ni < 4; ++ni)
                acc[mi][ni] = __builtin_amdgcn_mfma_f32_16x16x32_bf16(a[mi], bb[ni], acc[mi][ni], 0, 0, 0);
    }
    __syncthreads();   // b1_s visible for chi_out below

    // ---- a1 epilogue: += dchi . Wda + b, store fp32 ----
#pragma unroll
    for (int mi = 0; mi < 4; ++mi) {
        float d[4][4];  // [r][l]
#pragma unroll
        for (int r = 0; r < 4; ++r) {
            const float* dr = &dchi_s[(wm + mi * 16 + q * 4 + r) * 4];
            d[r][0] = dr[0]; d[r][1] = dr[1]; d[r][2] = dr[2]; d[r][3] = dr[3];
        }
#pragma unroll
        for (int ni = 0; ni < 4; ++ni) {
            const int col = wn + ni * 16 + l16;
            const float bc = b_s[col];
            const float w0 = Wda_s[0 * 128 + col], w1 = Wda_s[1 * 128 + col];
            const float w2 = Wda_s[2 * 128 + col], w3 = Wda_s[3 * 128 + col];
#pragma unroll
            for (int r = 0; r < 4; ++r) {
                const int row = wm + mi * 16 + q * 4 + r;
                const long long rg = row0 + row;
                if (rg < n) {
                    float v = acc[mi][ni][r] + bc
                            + d[r][0] * w0 + d[r][1] * w1 + d[r][2] * w2 + d[r][3] * w3;
                    a1_out[rg * F + col] = v;
                }
            }
        }
    }

    // ---- chi_out = b1[:, seg] * chi ----
    {
        const int row = t >> 1;
        const int half = t & 1;
        const long long rg = row0 + row;
        if (rg < n) {
            const float* c = &chi_s[row * 16 + half * 8];
            const float* bb1 = &b1_s[row * 4];
            float o[8];
            if (half == 0) {
                // m = 0..7 : seg = 0,1,1,1,2,2,2,2
                o[0] = c[0] * bb1[0];
                o[1] = c[1] * bb1[1]; o[2] = c[2] * bb1[1]; o[3] = c[3] * bb1[1];
                o[4] = c[4] * bb1[2]; o[5] = c[5] * bb1[2]; o[6] = c[6] * bb1[2]; o[7] = c[7] * bb1[2];
            } else {
                // m = 8..15 : seg = 2,3,3,3,3,3,3,3
                o[0] = c[0] * bb1[2];
                o[1] = c[1] * bb1[3]; o[2] = c[2] * bb1[3]; o[3] = c[3] * bb1[3];
                o[4] = c[4] * bb1[3]; o[5] = c[5] * bb1[3]; o[6] = c[6] * bb1[3]; o[7] = c[7] * bb1[3];
            }
            float4* dst = reinterpret_cast<float4*>(chi_out + rg * MTOT + half * 8);
            dst[0] = make_float4(o[0], o[1], o[2], o[3]);
            dst[1] = make_float4(o[4], o[5], o[6], o[7]);
        }
    }
}

extern "C" void kernel_launch(void* const* d_in, const int* in_sizes, int n_in,
                              void* d_out, int out_size, void* d_ws, size_t ws_size,
                              hipStream_t stream) {
    const float* x   = (const float*)d_in[0];
    const float* chi = (const float*)d_in[1];
    // d_in[2] = point_mask (unused by the reference computation)
    const float* W   = (const float*)d_in[3];
    const float* b   = (const float*)d_in[4];

    const int n = in_sizes[0] / F;
    unsigned short* Wt = (unsigned short*)d_ws;   // 128*128*2 = 32 KB
    float* a1  = (float*)d_out;
    float* chio = a1 + (long long)n * F;

    prep_wt<<<64, 256, 0, stream>>>(W, Wt);
    const int nb = (n + 127) / 128;
    interaction_kernel<<<nb, 256, 0, stream>>>(x, chi, W, b, Wt, a1, chio, n);
}